// Round 5
// baseline (8684.023 us; speedup 1.0000x reference)
//
#include <hip/hip_runtime.h>
#include <math.h>

// ---------------- problem constants ----------------
constexpr int U  = 160;
constexpr int LN = 512;
constexpr int NN = 400;
constexpr int S  = 16;
constexpr int W_ = 64;
constexpr float C_VIOL = 2.0e4f;
constexpr int N_ITERS = 500;
constexpr int N_POWER = 30;

#define WGN 32
#define TPB 512
#define NTH (WGN*TPB)

// XCD mode: elect 32 WGs on one XCD, exchange via that XCD's (coherent) L2
// using sc0-only accesses. Requires buffer-load builtins for sc0 loads.
#if defined(__has_builtin)
# if __has_builtin(__builtin_amdgcn_make_buffer_rsrc) && \
     __has_builtin(__builtin_amdgcn_raw_ptr_buffer_load_b128) && \
     __has_builtin(__builtin_amdgcn_raw_ptr_buffer_load_b32)
#  define XCD_MODE 1
# endif
#endif

#ifdef XCD_MODE
# define LAUNCH_WGN 256
#else
# define LAUNCH_WGN WGN
#endif

constexpr int al4(int x){ return (x+3)&~3; }

// ---------------- ws layout (floats) ----------------
constexpr int O_HG    = 0;                 // Hg[LN][U]
constexpr int O_HGT   = O_HG   + LN*U;     // HgT[U][LN]
constexpr int O_PTDFT = O_HGT  + U*LN;     // PTDFT[NN][LN]
constexpr int O_HW    = O_PTDFT+ NN*LN;    // Hw[LN][W]
constexpr int O_PDL   = O_HW   + LN*W_;    // node_L@Pd [NN]
constexpr int O_CF    = al4(O_PDL + NN);   // const_flow [LN]
constexpr int O_B3    = O_CF   + LN;
constexpr int O_B4    = O_B3   + LN;
constexpr int O_BWS   = O_B4   + LN;       // b_ws[LN][S]
constexpr int O_BE1   = O_BWS  + LN*S;
constexpr int O_BE2   = al4(O_BE1 + 1);    // [S]
// mutable exchange
constexpr int O_MUT   = al4(O_BE2 + S);
constexpr int O_XBP   = O_MUT;             // [160] xb_p
constexpr int O_XFIN  = O_XBP  + 160;      // [160] final p
constexpr int O_DIFF  = O_XFIN + 160;      // [160][16]
constexpr int O_SDIFF = O_DIFF + 2560;     // [400]
constexpr int O_S78   = al4(O_SDIFF+400);  // [512][16]
constexpr int O_SW    = O_S78  + 8192;     // [512][2]: (w34, s78s)
constexpr int O_Z     = O_SW   + 1024;     // [20]: 0=z1 1=zs 2..17=z2
constexpr int O_PART  = O_Z    + 20;       // [32][20]
constexpr int O_ZEND  = O_PART + 640;
constexpr int O_N2    = O_ZEND;            // [32]  (atomic, MALL)
constexpr int O_EQ1   = O_N2   + 32;       // [32]
constexpr int O_EQ2   = O_EQ1  + 32;       // [32][16]
constexpr int O_EQS   = O_EQ2  + 512;      // [32]
constexpr int O_ARR   = O_EQS  + 32;       // [32*16] barrier flags (64B spaced)
constexpr int O_ELC   = O_ARR  + WGN*16;   // [8*16] per-XCD election counters
constexpr int O_ELT   = O_ELC  + 128;      // total election counter
constexpr int WSF     = O_ELT  + 16;

// ---------------- LDS layout (floats) ----------------
constexpr int L_SACC = 0;                  // [20]
constexpr int L_P    = al4(L_SACC + 20);   // [32][20] (WG0 stage of PART)
constexpr int L_DYN  = al4(L_P + 640);
// phase Y:
constexpr int L_XP = L_DYN;                // [160]
constexpr int L_SD = L_XP + 160;           // [400]
constexpr int L_DF = L_SD + 400;           // [160][17]
// phase X:
constexpr int D_S78T = L_DYN;              // [16][516]
constexpr int D_W34  = D_S78T + 16*516;    // [512]
constexpr int D_S78S = D_W34 + 512;        // [512]
constexpr int L_TOT  = D_S78S + 512;

// ---------------- device helpers ----------------
typedef __attribute__((ext_vector_type(4))) float fx4;

__device__ __forceinline__ float wred64(float v){
#pragma unroll
  for (int o = 32; o > 0; o >>= 1) v += __shfl_xor(v, o, 64);
  return v;
}
__device__ __forceinline__ float red16(float v){
  v += __shfl_xor(v, 1, 64); v += __shfl_xor(v, 2, 64);
  v += __shfl_xor(v, 4, 64); v += __shfl_xor(v, 8, 64);
  return v;
}
__device__ __forceinline__ float redchunk(float v){
  v += __shfl_xor(v, 16, 64); v += __shfl_xor(v, 32, 64);
  return v;
}
__device__ __forceinline__ float dot4(float4 a, float4 b){
  return a.x*b.x + a.y*b.y + a.z*b.z + a.w*b.w;
}
// agent-scope (MALL) accessors — used for atomics-written scalars + fallback
__device__ __forceinline__ float ald(const float* p){
  return __hip_atomic_load(p, __ATOMIC_RELAXED, __HIP_MEMORY_SCOPE_AGENT);
}
__device__ __forceinline__ void ast(float* p, float v){
  __hip_atomic_store(p, v, __ATOMIC_RELAXED, __HIP_MEMORY_SCOPE_AGENT);
}
__device__ __forceinline__ float2 ald2(const float* p){
  unsigned long long q = __hip_atomic_load((const unsigned long long*)p,
                          __ATOMIC_RELAXED, __HIP_MEMORY_SCOPE_AGENT);
  union { unsigned long long q; float2 f; } c; c.q = q; return c.f;
}
__device__ __forceinline__ void ast2(float* p, float2 v){
  union { float2 f; unsigned long long q; } c; c.f = v;
  __hip_atomic_store((unsigned long long*)p, c.q,
                     __ATOMIC_RELAXED, __HIP_MEMORY_SCOPE_AGENT);
}
__device__ __forceinline__ unsigned aldu(const unsigned* p){
  return __hip_atomic_load(p, __ATOMIC_RELAXED, __HIP_MEMORY_SCOPE_AGENT);
}
__device__ __forceinline__ void astu(unsigned* p, unsigned v){
  __hip_atomic_store(p, v, __ATOMIC_RELAXED, __HIP_MEMORY_SCOPE_AGENT);
}

#ifdef XCD_MODE
// sc0-only stores (L1-bypass, L2-coherent within an XCD)
__device__ __forceinline__ void st1(float* p, float v){
  asm volatile("global_store_dword %0, %1, off sc0" :: "v"(p), "v"(v) : "memory");
}
__device__ __forceinline__ void st2(float* p, float2 v){
  asm volatile("global_store_dwordx2 %0, %1, off sc0" :: "v"(p), "v"(v) : "memory");
}
__device__ __forceinline__ void sti(unsigned* p, unsigned v){
  asm volatile("global_store_dword %0, %1, off sc0" :: "v"(p), "v"(v) : "memory");
}
#else
__device__ __forceinline__ void st1(float* p, float v){ ast(p, v); }
__device__ __forceinline__ void st2(float* p, float2 v){ ast2(p, v); }
__device__ __forceinline__ void sti(unsigned* p, unsigned v){ astu(p, v); }
#endif

// ---------------- setup kernels ----------------
__global__ void k_zero(float* ws){
  int gt = blockIdx.x*blockDim.x + threadIdx.x;
  int nt = gridDim.x*blockDim.x;
  for (int i = gt; i < WSF - O_MUT; i += nt){
    int a = O_MUT + i;
    float v = 0.f;
    if (a >= O_XBP && a < O_XBP + 160) v = 1.f;   // power v0: p = ones
    if (a == O_EQ1) v = (float)U;                 // eq1(ones) = sum p
    ws[a] = v;
  }
}

__global__ void k_pdl(const float* nL, const float* Pd, float* ws){
  int n = blockIdx.x; int lane = threadIdx.x;
  float p = 0.f;
  for (int m = lane; m < NN; m += 64) p += nL[n*NN+m]*Pd[m];
  p = wred64(p);
  if (lane == 0) ws[O_PDL+n] = p;
}

__global__ void k_hg(const float* PTDF, const float* nG, float* ws){
  int l = blockIdx.x, u = threadIdx.x;
  float acc = 0.f;
  for (int n = 0; n < NN; ++n) acc += PTDF[l*NN+n]*nG[n*U+u];
  ws[O_HG + l*U + u]  = acc;
  ws[O_HGT + u*LN + l] = acc;
}

__global__ void k_hw(const float* PTDF, const float* nW, float* ws){
  int l = blockIdx.x, w = threadIdx.x;
  float acc = 0.f;
  for (int n = 0; n < NN; ++n) acc += PTDF[l*NN+n]*nW[n*W_+w];
  ws[O_HW + l*W_ + w] = acc;
}

__global__ void k_tp(const float* PTDF, float* ws){
  int n = blockIdx.x;
  for (int l = threadIdx.x; l < LN; l += blockDim.x)
    ws[O_PTDFT + n*LN + l] = PTDF[l*NN + n];
}

__global__ void k_misc(const float* PTDF, const float* w_exp, const float* w_scen,
                       const float* Cap, float* ws){
  int l = blockIdx.x; int lane = threadIdx.x;
  float part = ws[O_HW + l*W_ + lane]*w_exp[lane];
  for (int n = lane; n < NN; n += 64) part -= PTDF[l*NN+n]*ws[O_PDL+n];
  float cfv = wred64(part);
  if (lane == 0){
    ws[O_CF+l] = cfv;
    ws[O_B3+l] = Cap[l] - cfv;
    ws[O_B4+l] = Cap[l] + cfv;
  }
  int s = lane & 15, ch = lane >> 4;
  float bp = 0.f;
  for (int w = ch*16; w < ch*16+16; ++w) bp += ws[O_HW + l*W_ + w]*w_scen[s*W_+w];
  bp = redchunk(bp);
  if (lane < 16) ws[O_BWS + l*S + s] = bp;
}

__global__ void k_scal(const float* Pd, const float* w_exp, const float* w_scen, float* ws){
  __shared__ float sr[256];
  int tid = threadIdx.x;
  float p = 0.f;
  for (int i = tid; i < NN; i += 256) p += Pd[i];
  for (int i = tid; i < W_; i += 256) p -= w_exp[i];
  sr[tid] = p; __syncthreads();
  for (int o = 128; o > 0; o >>= 1){ if (tid < o) sr[tid] += sr[tid+o]; __syncthreads(); }
  if (tid == 0) ws[O_BE1] = sr[0];
  if (tid < S){
    float a = 0.f;
    for (int w = 0; w < W_; ++w) a += w_scen[tid*W_+w];
    ws[O_BE2+tid] = -a;
  }
}

// ---------------- persistent solver ----------------
extern "C" __global__ void __launch_bounds__(TPB)
k_solver(float* __restrict__ ws, const float* __restrict__ Pmax,
         const float* __restrict__ Cost, const float* __restrict__ Crup,
         const float* __restrict__ Crdn, const float* __restrict__ PTDF,
         const float* __restrict__ Cap, float* __restrict__ out)
{
  const int tid  = threadIdx.x;
  const int lane = tid & 63;
  const int wv   = tid >> 6;
  const int s = lane & 15, ch = lane >> 4;
  unsigned nbar = 0;
  __shared__ __align__(16) float lds[L_TOT];
  __shared__ int s_vb;

#ifdef XCD_MODE
  // ---- election: pick 32 WGs on the most-populated XCD ----
  if (tid == 0){
    int xcc;
    asm volatile("s_getreg_b32 %0, hwreg(HW_REG_XCC_ID)" : "=s"(xcc));
    xcc &= 7;
    int* elc = (int*)(ws + O_ELC);
    int* elt = (int*)(ws + O_ELT);
    int rank = __hip_atomic_fetch_add(&elc[xcc*16], 1, __ATOMIC_RELAXED,
                                      __HIP_MEMORY_SCOPE_AGENT);
    __threadfence();
    __hip_atomic_fetch_add(elt, 1, __ATOMIC_RELEASE, __HIP_MEMORY_SCOPE_AGENT);
    while (__hip_atomic_load(elt, __ATOMIC_ACQUIRE, __HIP_MEMORY_SCOPE_AGENT)
           < LAUNCH_WGN)
      __builtin_amdgcn_s_sleep(2);
    __threadfence();
    int best = 0, bc = -1;
    for (int x = 0; x < 8; ++x){
      int c = __hip_atomic_load(&elc[x*16], __ATOMIC_RELAXED,
                                __HIP_MEMORY_SCOPE_AGENT);
      if (c > bc){ bc = c; best = x; }
    }
    s_vb = (xcc == best && rank < WGN) ? rank : -1;
  }
  __syncthreads();
  const int vbid = s_vb;
  if (vbid < 0) return;
#else
  s_vb = blockIdx.x;
  __syncthreads();
  const int vbid = s_vb;
#endif

  const int gw   = vbid*8 + wv;        // 0..255
  const int gtid = vbid*TPB + tid;

#ifdef XCD_MODE
  auto wrs = __builtin_amdgcn_make_buffer_rsrc((void*)ws, (short)0, -1, 0x00020000);
  auto LDC4 = [&](int e)->fx4{ return __builtin_bit_cast(fx4,
       __builtin_amdgcn_raw_ptr_buffer_load_b128(wrs, e*4, 0, 1)); };
  auto LD1  = [&](int e)->float{ return __builtin_bit_cast(float,
       __builtin_amdgcn_raw_ptr_buffer_load_b32(wrs, e*4, 0, 1)); };
  auto LDIu = [&](int e)->unsigned{ return __builtin_bit_cast(unsigned,
       __builtin_amdgcn_raw_ptr_buffer_load_b32(wrs, e*4, 0, 1)); };
#else
  auto LDC4 = [&](int e)->fx4{
    float2 a = ald2(ws+e), b = ald2(ws+e+2);
    fx4 v; v.x=a.x; v.y=a.y; v.z=b.x; v.w=b.y; return v;
  };
  auto LD1  = [&](int e)->float{ return ald(ws+e); };
  auto LDIu = [&](int e)->unsigned{ return aldu((const unsigned*)(ws+e)); };
#endif

  const bool isU = (gw < 80);          // waves 0..79 (WGs 0..9): u = 2gw,2gw+1
  const int nbase = gw - 80;           // waves 80..255: n = nbase + 176r

  // persistent register state
  float xp[2],xru[2],xrd[2],xpu[2],xpd[2];
  float ry1[2],ry2[2],ry5[2],ry6[2];
  float xsu[3],xsd[3];
  float ly3[2],ly4[2],ly7[2],ly8[2];
  float rz1=0.f, rz2=0.f;
  float tau=0.f, sig=0.f;
#pragma unroll
  for (int r=0;r<2;++r){ xp[r]=xru[r]=xrd[r]=xpu[r]=xpd[r]=1.f;
                         ry1[r]=ry2[r]=ry5[r]=ry6[r]=0.f;
                         ly3[r]=ly4[r]=ly7[r]=ly8[r]=0.f; }
#pragma unroll
  for (int r=0;r<3;++r){ xsu[r]=xsd[r]=1.f; }

  // ---- grid barrier: per-WG monotonic flags, all-to-all poll ----
  unsigned* arr = (unsigned*)(ws + O_ARR);
  auto gbar = [&](){
    ++nbar;
    asm volatile("s_waitcnt vmcnt(0)" ::: "memory");  // drain my stores (incl. asm sc0)
    __syncthreads();
    if (tid < WGN){
      if (tid == vbid) sti(arr + vbid*16, nbar);
      while (LDIu(O_ARR + tid*16) < nbar){ asm volatile("" ::: "memory"); }
    }
    __syncthreads();
  };

  // ---- phase Y: per-line A-apply (power) / dual update (pdhg) ----
  auto phaseY = [&](bool pd, int k){
    float scl = 1.f;
    if (!pd && k > 0) scl = 1.f/sqrtf(ald(ws+O_N2+k));
    for (int i = tid; i < 40; i += TPB){ ((fx4*)(lds+L_XP))[i] = LDC4(O_XBP+4*i); }
    for (int i = tid; i < 100; i += TPB){ ((fx4*)(lds+L_SD))[i] = LDC4(O_SDIFF+4*i); }
    for (int i = tid; i < 640; i += TPB){
      fx4 v = LDC4(O_DIFF+4*i);
      int e = 4*i, uu = e >> 4, s0 = e & 15;
      float* d = lds + L_DF + uu*17 + s0;
      d[0]=v.x; d[1]=v.y; d[2]=v.z; d[3]=v.w;
    }
    if (pd && vbid == 0){
      for (int i = tid; i < 160; i += TPB){ ((fx4*)(lds+L_P))[i] = LDC4(O_PART+4*i); }
    }
    __syncthreads();

    if (pd && vbid == 0 && wv == 7){
      float acc = 0.f;
      if (lane < 18){
        for (int i = 0; i < WGN; ++i) acc += lds[L_P + i*20 + lane];
      }
      float susd = __shfl(acc, 17, 64);
      float ae1  = __shfl(acc, 16, 64);
      if (lane < 16){
        rz2 += sig*((acc + susd) - ws[O_BE2+lane]);
        st1(ws+O_Z+2+lane, rz2);
      }
      float zst = red16((lane < 16) ? rz2 : 0.f);
      if (lane == 0) st1(ws+O_Z+1, zst);
      if (lane == 16){ rz1 += sig*(ae1 - ws[O_BE1]); st1(ws+O_Z+0, rz1); }
    }

#pragma unroll
    for (int j = 0; j < 2; ++j){
      const int l = 2*gw + j;
      const float* hg = ws + O_HG + l*U;       // plain, L2-cached read-only
      float a = hg[lane]*lds[L_XP+lane] + hg[lane+64]*lds[L_XP+lane+64];
      if (lane < 32) a += hg[lane+128]*lds[L_XP+lane+128];
      float fp = wred64(a);
      const float4* pr  = (const float4*)(PTDF + l*NN);
      const float4* sd4 = (const float4*)(lds + L_SD);
      float b = dot4(pr[lane], sd4[lane]);
      if (lane < 36) b += dot4(pr[lane+64], sd4[lane+64]);
      float pn = wred64(b);
      const float* hgc = hg + ch*40;
      const float* dfc = lds + L_DF + (ch*40)*17 + s;
      float sc = 0.f;
#pragma unroll 8
      for (int i = 0; i < 40; ++i) sc += hgc[i]*dfc[i*17];
      sc = redchunk(sc);
      float scen = sc + fp + pn;
      float b3l = ws[O_B3+l], b4l = ws[O_B4+l];
      float sv;
      if (pd){
        float bw = ws[O_BWS + l*16 + s];
        ly7[j] = fmaxf(ly7[j] + sig*( scen - (b3l - bw)), 0.f);
        ly8[j] = fmaxf(ly8[j] + sig*(-scen - (b4l + bw)), 0.f);
        sv = ly7[j] - ly8[j];
        ly3[j] = fmaxf(ly3[j] + sig*( fp - b3l), 0.f);
        ly4[j] = fmaxf(ly4[j] + sig*(-fp - b4l), 0.f);
      } else {
        sv = 2.f*scen*scl;
        ly3[j] = fp*scl; ly4[j] = -fp*scl;
      }
      if (lane < 16) st1(ws+O_S78 + l*16 + s, sv);
      float ssum = red16(sv);
      if (lane == 0) st2(ws+O_SW + 2*l, make_float2(ly3[j]-ly4[j]+ssum, ssum));
    }
  };

  // ---- phase X: AT-apply + primal update ----
  auto phaseX = [&](bool pd, int k, bool last){
    if (tid < 20) lds[L_SACC+tid] = 0.f;
    if (vbid < 10){
      for (int i = tid; i < 2048; i += TPB){
        fx4 v = LDC4(O_S78+4*i);
        int e = 4*i, ll = e >> 4, s0 = e & 15;
        lds[D_S78T + (s0  )*516 + ll] = v.x;
        lds[D_S78T + (s0+1)*516 + ll] = v.y;
        lds[D_S78T + (s0+2)*516 + ll] = v.z;
        lds[D_S78T + (s0+3)*516 + ll] = v.w;
      }
      for (int i = tid; i < 256; i += TPB){
        fx4 v = LDC4(O_SW+4*i);
        lds[D_W34+2*i] = v.x; lds[D_W34+2*i+1] = v.z;
      }
    } else {
      for (int i = tid; i < 256; i += TPB){
        fx4 v = LDC4(O_SW+4*i);
        lds[D_S78S+2*i] = v.y; lds[D_S78S+2*i+1] = v.w;
      }
    }
    float scl = 1.f, z1v, z2v, zsv;
    if (pd){
      z1v = LD1(O_Z+0); z2v = LD1(O_Z+2+s); zsv = LD1(O_Z+1);
    } else {
      if (k > 0) scl = 1.f/sqrtf(ald(ws+O_N2+k));
      z1v = ald(ws+O_EQ1+k)*scl;
      z2v = (ald(ws+O_EQ2+k*16+s) + ald(ws+O_EQS+k))*scl;
      zsv = red16(z2v);
    }
    __syncthreads();

    float n2p=0.f, e1p=0.f, a2p=0.f, susdp=0.f, dap=0.f;
    if (isU){
#pragma unroll
      for (int r = 0; r < 2; ++r){
        int u = 2*gw + r;
        float y1,y2,y5,y6;
        if (pd){ y1=ry1[r]; y2=ry2[r]; y5=ry5[r]; y6=ry6[r]; }
        else {
          y1=(xp[r]+xru[r])*scl; y2=(xrd[r]-xp[r])*scl;
          y5=(xpu[r]-xru[r])*scl; y6=(xpd[r]-xrd[r])*scl;
        }
        const float* HT = ws + O_HGT + u*LN;   // plain, L2-cached
        const float4* ht4 = (const float4*)HT;
        const float4* w4  = (const float4*)(lds + D_W34);
        float g = dot4(ht4[lane], w4[lane]) + dot4(ht4[lane+64], w4[lane+64]);
        float gdot = wred64(g);
        // h-dot: chunk-interleaved (4k+ch) to break stride-128 bank aliasing
        const float4* sc4f = (const float4*)(lds + D_S78T + s*516);
        float h = 0.f;
#pragma unroll 8
        for (int k2 = 0; k2 < 32; ++k2) h += dot4(ht4[4*k2+ch], sc4f[4*k2+ch]);
        h = redchunk(h);
        float t5 = red16(y5), t6 = red16(y6);
        float gpu = y5 + h + z2v;
        float gpd = y6 - h - z2v;
        float gp  = y1 - y2 + gdot + z1v;
        float gru = y1 - t5;
        float grd = y2 - t6;
        if (pd){
          float xo;
          xo=xp[r];  xp[r] =fmaxf(xo-tau*(Cost[u]+gp ),0.f); float xbp_=2.f*xp[r] -xo;
          xo=xru[r]; xru[r]=fmaxf(xo-tau*(Crup[u]+gru),0.f); float xbru=2.f*xru[r]-xo;
          xo=xrd[r]; xrd[r]=fmaxf(xo-tau*(Crdn[u]+grd),0.f); float xbrd=2.f*xrd[r]-xo;
          xo=xpu[r]; xpu[r]=fmaxf(xo-tau*gpu,0.f);           float xbpu=2.f*xpu[r]-xo;
          xo=xpd[r]; xpd[r]=fmaxf(xo-tau*gpd,0.f);           float xbpd=2.f*xpd[r]-xo;
          float d = xbpu - xbpd;
          if (lane == 0){ st1(ws+O_XBP+u, xbp_); e1p += xbp_; }
          if (lane < 16){ st1(ws+O_DIFF+u*16+s, d); a2p += d; }
          ry1[r]=fmaxf(y1+sig*(xbp_+xbru-Pmax[u]),0.f);
          ry2[r]=fmaxf(y2+sig*(xbrd-xbp_),0.f);
          ry5[r]=fmaxf(y5+sig*(xbpu-xbru),0.f);
          ry6[r]=fmaxf(y6+sig*(xbpd-xbrd),0.f);
          if (last){
            if (lane == 0){
              st1(ws+O_XFIN+u, xp[r]);
              dap += Cost[u]*xp[r] + Crup[u]*xru[r] + Crdn[u]*xrd[r];
              out[u]=xp[r]; out[U+u]=xru[r]; out[2*U+u]=xrd[r];
            }
            if (lane < 16){
              out[3*U + u*16 + s] = xpu[r];
              out[3*U + U*S + u*16 + s] = xpd[r];
            }
          }
        } else {
          xp[r]=gp; xru[r]=gru; xrd[r]=grd; xpu[r]=gpu; xpd[r]=gpd;
          float d = gpu - gpd;
          if (lane == 0){ st1(ws+O_XBP+u, gp); e1p += gp; n2p += gp*gp+gru*gru+grd*grd; }
          if (lane < 16){ st1(ws+O_DIFF+u*16+s, d); a2p += d; n2p += gpu*gpu+gpd*gpd; }
        }
      }
    } else {
      const float4* ss4 = (const float4*)(lds + D_S78S);
#pragma unroll
      for (int r = 0; r < 3; ++r){
        int n = nbase + 176*r;
        if (n >= NN) break;
        const float* PT = ws + O_PTDFT + n*LN;  // plain, L2-cached
        const float4* pt4 = (const float4*)PT;
        float g = dot4(pt4[lane], ss4[lane]) + dot4(pt4[lane+64], ss4[lane+64]);
        float pt = wred64(g);
        if (pd){
          float g1 = C_VIOL + pt + zsv, g2 = C_VIOL - pt - zsv;
          float xo = xsu[r]; xsu[r] = fmaxf(xo - tau*g1, 0.f); float xb1 = 2.f*xsu[r]-xo;
          xo = xsd[r];       xsd[r] = fmaxf(xo - tau*g2, 0.f); float xb2 = 2.f*xsd[r]-xo;
          if (lane == 0){
            st1(ws+O_SDIFF+n, xb1-xb2); susdp += xb1-xb2;
            if (last) dap += C_VIOL*(xsu[r] + xsd[r]);
          }
        } else {
          float gsu = pt + zsv;
          xsu[r] = gsu; xsd[r] = -gsu;
          if (lane == 0){ st1(ws+O_SDIFF+n, 2.f*gsu); susdp += 2.f*gsu; n2p += 2.f*gsu*gsu; }
        }
      }
    }
    float r1 = wred64(e1p);
    float r2 = wred64(susdp);
    float r3 = wred64(n2p + dap);
    if (lane == 0){
      atomicAdd(&lds[L_SACC+16], r1);
      atomicAdd(&lds[L_SACC+17], r2);
      atomicAdd(&lds[L_SACC+18], r3);
    }
    if (lane < 16) atomicAdd(&lds[L_SACC+s], a2p);
    __syncthreads();
    if (pd){
      if (tid < 10)
        st2(ws+O_PART+vbid*20+2*tid, make_float2(lds[L_SACC+2*tid], lds[L_SACC+2*tid+1]));
    } else {
      if (tid < 16) atomicAdd(&ws[O_EQ2+(k+1)*16+tid], lds[L_SACC+tid]);
      else if (tid == 16) atomicAdd(&ws[O_EQ1+k+1], lds[L_SACC+16]);
      else if (tid == 17) atomicAdd(&ws[O_EQS+k+1], lds[L_SACC+17]);
      else if (tid == 18) atomicAdd(&ws[O_N2 +k+1], lds[L_SACC+18]);
    }
  };

  // ---- power iteration ----
  for (int kk = 0; kk <= N_POWER; ++kk){
    phaseY(false, kk); gbar();
    phaseX(false, kk, false); gbar();
  }

  // ---- step sizes ----
  {
    float Lop = sqrtf(sqrtf(ald(ws+O_N2+31)));
    tau = 0.9f/Lop; sig = 0.9f/Lop;
  }

  // ---- transition: zero register + exchange state ----
#pragma unroll
  for (int r=0;r<2;++r){ xp[r]=xru[r]=xrd[r]=xpu[r]=xpd[r]=0.f;
                         ry1[r]=ry2[r]=ry5[r]=ry6[r]=0.f;
                         ly3[r]=ly4[r]=ly7[r]=ly8[r]=0.f; }
#pragma unroll
  for (int r=0;r<3;++r){ xsu[r]=xsd[r]=0.f; }
  rz1 = rz2 = 0.f;
  for (int i = gtid; i < O_ZEND - O_MUT; i += NTH) st1(ws+O_MUT+i, 0.f);
  gbar();

  // ---- PDHG ----
  for (int it = 0; it < N_ITERS; ++it){
    phaseX(true, it, it == N_ITERS-1); gbar();
    if (it < N_ITERS-1){ phaseY(true, it); gbar(); }
  }

  // ---- epilogue: flows + DA cost ----
  for (int i = tid; i < 40; i += TPB){ ((fx4*)(lds+L_XP))[i] = LDC4(O_XFIN+4*i); }
  __syncthreads();
#pragma unroll
  for (int j = 0; j < 2; ++j){
    const int l = 2*gw + j;
    const float* hg = ws + O_HG + l*U;
    float a = hg[lane]*lds[L_XP+lane] + hg[lane+64]*lds[L_XP+lane+64];
    if (lane < 32) a += hg[lane+128]*lds[L_XP+lane+128];
    float flow = wred64(a) + ws[O_CF+l];
    if (lane == 0){
      out[3*U + 2*U*S + l]      = Cap[l] - flow;
      out[3*U + 2*U*S + LN + l] = Cap[l] + flow;
    }
  }
  if (vbid == 0 && wv == 0){
    float da = (lane < WGN) ? LD1(O_PART+lane*20+18) : 0.f;
    da = wred64(da);
    if (lane == 0) out[3*U + 2*U*S + 2*LN] = da;
  }
}

// ---------------- host entry ----------------
extern "C" void kernel_launch(void* const* d_in, const int* in_sizes, int n_in,
                              void* d_out, int out_size, void* d_ws, size_t ws_size,
                              hipStream_t stream){
  const float* w_scen = (const float*)d_in[0];
  const float* Pmax   = (const float*)d_in[1];
  const float* Cost   = (const float*)d_in[2];
  const float* Crup   = (const float*)d_in[3];
  const float* Crdn   = (const float*)d_in[4];
  const float* PTDF   = (const float*)d_in[5];
  const float* nG     = (const float*)d_in[6];
  const float* nW     = (const float*)d_in[7];
  const float* nL     = (const float*)d_in[8];
  const float* Pd     = (const float*)d_in[9];
  const float* w_exp  = (const float*)d_in[10];
  const float* Cap    = (const float*)d_in[11];
  float* ws  = (float*)d_ws;
  float* out = (float*)d_out;

  k_zero<<<dim3(64),  dim3(256), 0, stream>>>(ws);
  k_pdl <<<dim3(NN),  dim3(64),  0, stream>>>(nL, Pd, ws);
  k_hg  <<<dim3(LN),  dim3(U),   0, stream>>>(PTDF, nG, ws);
  k_hw  <<<dim3(LN),  dim3(W_),  0, stream>>>(PTDF, nW, ws);
  k_tp  <<<dim3(NN),  dim3(256), 0, stream>>>(PTDF, ws);
  k_misc<<<dim3(LN),  dim3(64),  0, stream>>>(PTDF, w_exp, w_scen, Cap, ws);
  k_scal<<<dim3(1),   dim3(256), 0, stream>>>(Pd, w_exp, w_scen, ws);
  k_solver<<<dim3(LAUNCH_WGN), dim3(TPB), 0, stream>>>(ws, Pmax, Cost, Crup, Crdn, PTDF, Cap, out);
}

// Round 6
// 6957.301 us; speedup vs baseline: 1.2482x; 1.2482x over previous
//
#include <hip/hip_runtime.h>
#include <math.h>

// ---------------- problem constants ----------------
constexpr int U  = 160;
constexpr int LN = 512;
constexpr int NN = 400;
constexpr int S  = 16;
constexpr int W_ = 64;
constexpr float C_VIOL = 2.0e4f;
constexpr int N_ITERS = 500;
constexpr int N_POWER = 30;

#define WGN 32
#define TPB 512
#define NTH (WGN*TPB)
#define LAUNCH_WGN 256   // elect 32 WGs on one XCD; others exit

constexpr int al4(int x){ return (x+3)&~3; }

// ---------------- ws layout (floats) ----------------
constexpr int O_HG    = 0;                 // Hg[LN][U]
constexpr int O_HGT   = O_HG   + LN*U;     // HgT[U][LN]
constexpr int O_PTDFT = O_HGT  + U*LN;     // PTDFT[NN][LN]
constexpr int O_HW    = O_PTDFT+ NN*LN;    // Hw[LN][W]
constexpr int O_PDL   = O_HW   + LN*W_;    // node_L@Pd [NN]
constexpr int O_CF    = al4(O_PDL + NN);   // const_flow [LN]
constexpr int O_B3    = O_CF   + LN;
constexpr int O_B4    = O_B3   + LN;
constexpr int O_BWS   = O_B4   + LN;       // b_ws[LN][S]
constexpr int O_BE1   = O_BWS  + LN*S;
constexpr int O_BE2   = al4(O_BE1 + 1);    // [S]
// mutable exchange (CU-scope, L2-resident on the elected XCD)
constexpr int O_MUT   = al4(O_BE2 + S);
constexpr int O_XBP   = O_MUT;             // [160] xb_p
constexpr int O_XFIN  = O_XBP  + 160;      // [160] final p
constexpr int O_DIFF  = O_XFIN + 160;      // [160][16]
constexpr int O_SDIFF = O_DIFF + 2560;     // [400]
constexpr int O_S78   = al4(O_SDIFF+400);  // [512][16]
constexpr int O_SW    = O_S78  + 8192;     // [512][2]: (w34, s78s)
constexpr int O_Z     = O_SW   + 1024;     // [20]: 0=z1 1=zs 2..17=z2
constexpr int O_PART  = O_Z    + 20;       // [32][20]
constexpr int O_ZEND  = O_PART + 640;
// device-atomic accumulators (MALL; agent-scope loads ONLY — never plain)
constexpr int O_N2    = O_ZEND;            // [32]
constexpr int O_EQ1   = O_N2   + 32;       // [32]
constexpr int O_EQ2   = O_EQ1  + 32;       // [32][16]
constexpr int O_EQS   = O_EQ2  + 512;      // [32]
constexpr int O_ARR   = O_EQS  + 32;       // [32*16] barrier flags (64B spaced)
constexpr int O_ELC   = O_ARR  + WGN*16;   // [8*16] per-XCD election counters
constexpr int O_ELT   = O_ELC  + 128;      // total election counter
constexpr int WSF     = O_ELT  + 16;

// ---------------- LDS layout (floats) ----------------
constexpr int L_SACC = 0;                  // [20]
constexpr int L_P    = al4(L_SACC + 20);   // [32][20] (WG0 stage of PART)
constexpr int L_DYN  = al4(L_P + 640);
// phase Y:
constexpr int L_XP = L_DYN;                // [160]
constexpr int L_SD = L_XP + 160;           // [400]
constexpr int L_DF = L_SD + 400;           // [160][17]
// phase X:
constexpr int D_S78T = L_DYN;              // [16][516]
constexpr int D_W34  = D_S78T + 16*516;    // [512]
constexpr int D_S78S = D_W34 + 512;        // [512]
constexpr int L_TOT  = D_S78S + 512;

// ---------------- device helpers ----------------
__device__ __forceinline__ float wred64(float v){
#pragma unroll
  for (int o = 32; o > 0; o >>= 1) v += __shfl_xor(v, o, 64);
  return v;
}
__device__ __forceinline__ float red16(float v){
  v += __shfl_xor(v, 1, 64); v += __shfl_xor(v, 2, 64);
  v += __shfl_xor(v, 4, 64); v += __shfl_xor(v, 8, 64);
  return v;
}
__device__ __forceinline__ float redchunk(float v){
  v += __shfl_xor(v, 16, 64); v += __shfl_xor(v, 32, 64);
  return v;
}
__device__ __forceinline__ float dot4(float4 a, float4 b){
  return a.x*b.x + a.y*b.y + a.z*b.z + a.w*b.w;
}
// agent-scope (MALL) load — for device-atomic-written accumulators only
__device__ __forceinline__ float ald(const float* p){
  return __hip_atomic_load(p, __ATOMIC_RELAXED, __HIP_MEMORY_SCOPE_AGENT);
}
// workgroup-scope atomic load: forces a VECTOR load (not s_load/K$) at CU scope
__device__ __forceinline__ float wgld(const float* p){
  return __hip_atomic_load(p, __ATOMIC_RELAXED, __HIP_MEMORY_SCOPE_WORKGROUP);
}

// ---------------- setup kernels ----------------
__global__ void k_zero(float* ws){
  int gt = blockIdx.x*blockDim.x + threadIdx.x;
  int nt = gridDim.x*blockDim.x;
  for (int i = gt; i < WSF - O_MUT; i += nt){
    int a = O_MUT + i;
    float v = 0.f;
    if (a >= O_XBP && a < O_XBP + 160) v = 1.f;   // power v0: p = ones
    if (a == O_EQ1) v = (float)U;                 // eq1(ones) = sum p
    ws[a] = v;
  }
}

__global__ void k_pdl(const float* nL, const float* Pd, float* ws){
  int n = blockIdx.x; int lane = threadIdx.x;
  float p = 0.f;
  for (int m = lane; m < NN; m += 64) p += nL[n*NN+m]*Pd[m];
  p = wred64(p);
  if (lane == 0) ws[O_PDL+n] = p;
}

__global__ void k_hg(const float* PTDF, const float* nG, float* ws){
  int l = blockIdx.x, u = threadIdx.x;
  float acc = 0.f;
  for (int n = 0; n < NN; ++n) acc += PTDF[l*NN+n]*nG[n*U+u];
  ws[O_HG + l*U + u]  = acc;
  ws[O_HGT + u*LN + l] = acc;
}

__global__ void k_hw(const float* PTDF, const float* nW, float* ws){
  int l = blockIdx.x, w = threadIdx.x;
  float acc = 0.f;
  for (int n = 0; n < NN; ++n) acc += PTDF[l*NN+n]*nW[n*W_+w];
  ws[O_HW + l*W_ + w] = acc;
}

__global__ void k_tp(const float* PTDF, float* ws){
  int n = blockIdx.x;
  for (int l = threadIdx.x; l < LN; l += blockDim.x)
    ws[O_PTDFT + n*LN + l] = PTDF[l*NN + n];
}

__global__ void k_misc(const float* PTDF, const float* w_exp, const float* w_scen,
                       const float* Cap, float* ws){
  int l = blockIdx.x; int lane = threadIdx.x;
  float part = ws[O_HW + l*W_ + lane]*w_exp[lane];
  for (int n = lane; n < NN; n += 64) part -= PTDF[l*NN+n]*ws[O_PDL+n];
  float cfv = wred64(part);
  if (lane == 0){
    ws[O_CF+l] = cfv;
    ws[O_B3+l] = Cap[l] - cfv;
    ws[O_B4+l] = Cap[l] + cfv;
  }
  int s = lane & 15, ch = lane >> 4;
  float bp = 0.f;
  for (int w = ch*16; w < ch*16+16; ++w) bp += ws[O_HW + l*W_ + w]*w_scen[s*W_+w];
  bp = redchunk(bp);
  if (lane < 16) ws[O_BWS + l*S + s] = bp;
}

__global__ void k_scal(const float* Pd, const float* w_exp, const float* w_scen, float* ws){
  __shared__ float sr[256];
  int tid = threadIdx.x;
  float p = 0.f;
  for (int i = tid; i < NN; i += 256) p += Pd[i];
  for (int i = tid; i < W_; i += 256) p -= w_exp[i];
  sr[tid] = p; __syncthreads();
  for (int o = 128; o > 0; o >>= 1){ if (tid < o) sr[tid] += sr[tid+o]; __syncthreads(); }
  if (tid == 0) ws[O_BE1] = sr[0];
  if (tid < S){
    float a = 0.f;
    for (int w = 0; w < W_; ++w) a += w_scen[tid*W_+w];
    ws[O_BE2+tid] = -a;
  }
}

// ---------------- persistent solver ----------------
extern "C" __global__ void __launch_bounds__(TPB)
k_solver(float* __restrict__ ws, const float* __restrict__ Pmax,
         const float* __restrict__ Cost, const float* __restrict__ Crup,
         const float* __restrict__ Crdn, const float* __restrict__ PTDF,
         const float* __restrict__ Cap, float* __restrict__ out)
{
  const int tid  = threadIdx.x;
  const int lane = tid & 63;
  const int wv   = tid >> 6;
  const int s = lane & 15, ch = lane >> 4;
  unsigned nbar = 0;
  __shared__ __align__(16) float lds[L_TOT];
  __shared__ int s_vb;

  // ---- election: pick 32 WGs on the most-populated XCD (agent-scope ops) ----
  if (tid == 0){
    int xcc;
    asm volatile("s_getreg_b32 %0, hwreg(HW_REG_XCC_ID)" : "=s"(xcc));
    xcc &= 7;
    int* elc = (int*)(ws + O_ELC);
    int* elt = (int*)(ws + O_ELT);
    int rank = __hip_atomic_fetch_add(&elc[xcc*16], 1, __ATOMIC_RELAXED,
                                      __HIP_MEMORY_SCOPE_AGENT);
    __threadfence();
    __hip_atomic_fetch_add(elt, 1, __ATOMIC_RELEASE, __HIP_MEMORY_SCOPE_AGENT);
    while (__hip_atomic_load(elt, __ATOMIC_ACQUIRE, __HIP_MEMORY_SCOPE_AGENT)
           < LAUNCH_WGN)
      __builtin_amdgcn_s_sleep(2);
    __threadfence();
    int best = 0, bc = -1;
    for (int x = 0; x < 8; ++x){
      int c = __hip_atomic_load(&elc[x*16], __ATOMIC_RELAXED,
                                __HIP_MEMORY_SCOPE_AGENT);
      if (c > bc){ bc = c; best = x; }
    }
    s_vb = (xcc == best && rank < WGN) ? rank : -1;
  }
  __syncthreads();
  const int vbid = s_vb;
  if (vbid < 0) return;

  const int gw   = vbid*8 + wv;        // 0..255
  const int gtid = vbid*TPB + tid;

  // plain CU-scope accessors: exchange lives in the elected XCD's L2
  auto LDC4 = [&](int e)->float4{ return *(const float4*)(ws + e); };
  auto st1  = [&](float* p, float v){ *p = v; };
  auto st2  = [&](float* p, float2 v){ *(float2*)p = v; };

  const bool isU = (gw < 80);          // waves 0..79 (WGs 0..9): u = 2gw,2gw+1
  const int nbase = gw - 80;           // waves 80..255: n = nbase + 176r

  // persistent register state
  float xp[2],xru[2],xrd[2],xpu[2],xpd[2];
  float ry1[2],ry2[2],ry5[2],ry6[2];
  float xsu[3],xsd[3];
  float ly3[2],ly4[2],ly7[2],ly8[2];
  float rz1=0.f, rz2=0.f;
  float tau=0.f, sig=0.f;
#pragma unroll
  for (int r=0;r<2;++r){ xp[r]=xru[r]=xrd[r]=xpu[r]=xpd[r]=1.f;
                         ry1[r]=ry2[r]=ry5[r]=ry6[r]=0.f;
                         ly3[r]=ly4[r]=ly7[r]=ly8[r]=0.f; }
#pragma unroll
  for (int r=0;r<3;++r){ xsu[r]=xsd[r]=1.f; }

  // ---- L2-resident grid barrier: plain flags + vL1 invalidate in poll ----
  unsigned* arr = (unsigned*)(ws + O_ARR);
  auto gbar = [&](){
    ++nbar;
    asm volatile("s_waitcnt vmcnt(0)" ::: "memory");  // my stores acked in L2
    __syncthreads();
    if (tid < WGN){
      if (tid == vbid) *(volatile unsigned*)(arr + vbid*16) = nbar;
      volatile unsigned* f = (volatile unsigned*)(arr + tid*16);
      while (true){
        asm volatile("buffer_inv" ::: "memory");      // invalidate this CU's vL1
        asm volatile("s_waitcnt vmcnt(0)" ::: "memory");
        if (*f >= nbar) break;
      }
    }
    __syncthreads();   // all waves of this CU now see fresh L2 through clean L1
  };

  // ---- phase Y: per-line A-apply (power) / dual update (pdhg) ----
  auto phaseY = [&](bool pd, int k){
    float scl = 1.f;
    if (!pd && k > 0) scl = 1.f/sqrtf(ald(ws+O_N2+k));
    for (int i = tid; i < 40; i += TPB){ ((float4*)(lds+L_XP))[i] = LDC4(O_XBP+4*i); }
    for (int i = tid; i < 100; i += TPB){ ((float4*)(lds+L_SD))[i] = LDC4(O_SDIFF+4*i); }
    for (int i = tid; i < 640; i += TPB){
      float4 v = LDC4(O_DIFF+4*i);
      int e = 4*i, uu = e >> 4, s0 = e & 15;
      float* d = lds + L_DF + uu*17 + s0;
      d[0]=v.x; d[1]=v.y; d[2]=v.z; d[3]=v.w;
    }
    if (pd && vbid == 0){
      for (int i = tid; i < 160; i += TPB){ ((float4*)(lds+L_P))[i] = LDC4(O_PART+4*i); }
    }
    __syncthreads();

    if (pd && vbid == 0 && wv == 7){
      float acc = 0.f;
      if (lane < 18){
        for (int i = 0; i < WGN; ++i) acc += lds[L_P + i*20 + lane];
      }
      float susd = __shfl(acc, 17, 64);
      float ae1  = __shfl(acc, 16, 64);
      if (lane < 16){
        rz2 += sig*((acc + susd) - ws[O_BE2+lane]);
        st1(ws+O_Z+2+lane, rz2);
      }
      float zst = red16((lane < 16) ? rz2 : 0.f);
      if (lane == 0) st1(ws+O_Z+1, zst);
      if (lane == 16){ rz1 += sig*(ae1 - ws[O_BE1]); st1(ws+O_Z+0, rz1); }
    }

#pragma unroll
    for (int j = 0; j < 2; ++j){
      const int l = 2*gw + j;
      const float* hg = ws + O_HG + l*U;       // read-only, L2-cached
      float a = hg[lane]*lds[L_XP+lane] + hg[lane+64]*lds[L_XP+lane+64];
      if (lane < 32) a += hg[lane+128]*lds[L_XP+lane+128];
      float fp = wred64(a);
      const float4* pr  = (const float4*)(PTDF + l*NN);
      const float4* sd4 = (const float4*)(lds + L_SD);
      float b = dot4(pr[lane], sd4[lane]);
      if (lane < 36) b += dot4(pr[lane+64], sd4[lane+64]);
      float pn = wred64(b);
      const float* hgc = hg + ch*40;
      const float* dfc = lds + L_DF + (ch*40)*17 + s;
      float sc = 0.f;
#pragma unroll 8
      for (int i = 0; i < 40; ++i) sc += hgc[i]*dfc[i*17];
      sc = redchunk(sc);
      float scen = sc + fp + pn;
      float b3l = ws[O_B3+l], b4l = ws[O_B4+l];
      float sv;
      if (pd){
        float bw = ws[O_BWS + l*16 + s];
        ly7[j] = fmaxf(ly7[j] + sig*( scen - (b3l - bw)), 0.f);
        ly8[j] = fmaxf(ly8[j] + sig*(-scen - (b4l + bw)), 0.f);
        sv = ly7[j] - ly8[j];
        ly3[j] = fmaxf(ly3[j] + sig*( fp - b3l), 0.f);
        ly4[j] = fmaxf(ly4[j] + sig*(-fp - b4l), 0.f);
      } else {
        sv = 2.f*scen*scl;
        ly3[j] = fp*scl; ly4[j] = -fp*scl;
      }
      if (lane < 16) st1(ws+O_S78 + l*16 + s, sv);
      float ssum = red16(sv);
      if (lane == 0) st2(ws+O_SW + 2*l, make_float2(ly3[j]-ly4[j]+ssum, ssum));
    }
  };

  // ---- phase X: AT-apply + primal update ----
  auto phaseX = [&](bool pd, int k, bool last){
    if (tid < 20) lds[L_SACC+tid] = 0.f;
    if (vbid < 10){
      for (int i = tid; i < 2048; i += TPB){
        float4 v = LDC4(O_S78+4*i);
        int e = 4*i, ll = e >> 4, s0 = e & 15;
        lds[D_S78T + (s0  )*516 + ll] = v.x;
        lds[D_S78T + (s0+1)*516 + ll] = v.y;
        lds[D_S78T + (s0+2)*516 + ll] = v.z;
        lds[D_S78T + (s0+3)*516 + ll] = v.w;
      }
      for (int i = tid; i < 256; i += TPB){
        float4 v = LDC4(O_SW+4*i);
        lds[D_W34+2*i] = v.x; lds[D_W34+2*i+1] = v.z;
      }
    } else {
      for (int i = tid; i < 256; i += TPB){
        float4 v = LDC4(O_SW+4*i);
        lds[D_S78S+2*i] = v.y; lds[D_S78S+2*i+1] = v.w;
      }
    }
    float scl = 1.f, z1v, z2v, zsv;
    if (pd){
      z1v = wgld(ws+O_Z+0); z2v = ws[O_Z+2+s]; zsv = wgld(ws+O_Z+1);
    } else {
      if (k > 0) scl = 1.f/sqrtf(ald(ws+O_N2+k));
      z1v = ald(ws+O_EQ1+k)*scl;
      z2v = (ald(ws+O_EQ2+k*16+s) + ald(ws+O_EQS+k))*scl;
      zsv = red16(z2v);
    }
    __syncthreads();

    float n2p=0.f, e1p=0.f, a2p=0.f, susdp=0.f, dap=0.f;
    if (isU){
#pragma unroll
      for (int r = 0; r < 2; ++r){
        int u = 2*gw + r;
        float y1,y2,y5,y6;
        if (pd){ y1=ry1[r]; y2=ry2[r]; y5=ry5[r]; y6=ry6[r]; }
        else {
          y1=(xp[r]+xru[r])*scl; y2=(xrd[r]-xp[r])*scl;
          y5=(xpu[r]-xru[r])*scl; y6=(xpd[r]-xrd[r])*scl;
        }
        const float* HT = ws + O_HGT + u*LN;   // read-only, L2-cached
        const float4* ht4 = (const float4*)HT;
        const float4* w4  = (const float4*)(lds + D_W34);
        float g = dot4(ht4[lane], w4[lane]) + dot4(ht4[lane+64], w4[lane+64]);
        float gdot = wred64(g);
        const float4* sc4f = (const float4*)(lds + D_S78T + s*516);
        float h = 0.f;
#pragma unroll 8
        for (int k2 = 0; k2 < 32; ++k2) h += dot4(ht4[4*k2+ch], sc4f[4*k2+ch]);
        h = redchunk(h);
        float t5 = red16(y5), t6 = red16(y6);
        float gpu = y5 + h + z2v;
        float gpd = y6 - h - z2v;
        float gp  = y1 - y2 + gdot + z1v;
        float gru = y1 - t5;
        float grd = y2 - t6;
        if (pd){
          float xo;
          xo=xp[r];  xp[r] =fmaxf(xo-tau*(Cost[u]+gp ),0.f); float xbp_=2.f*xp[r] -xo;
          xo=xru[r]; xru[r]=fmaxf(xo-tau*(Crup[u]+gru),0.f); float xbru=2.f*xru[r]-xo;
          xo=xrd[r]; xrd[r]=fmaxf(xo-tau*(Crdn[u]+grd),0.f); float xbrd=2.f*xrd[r]-xo;
          xo=xpu[r]; xpu[r]=fmaxf(xo-tau*gpu,0.f);           float xbpu=2.f*xpu[r]-xo;
          xo=xpd[r]; xpd[r]=fmaxf(xo-tau*gpd,0.f);           float xbpd=2.f*xpd[r]-xo;
          float d = xbpu - xbpd;
          if (lane == 0){ st1(ws+O_XBP+u, xbp_); e1p += xbp_; }
          if (lane < 16){ st1(ws+O_DIFF+u*16+s, d); a2p += d; }
          ry1[r]=fmaxf(y1+sig*(xbp_+xbru-Pmax[u]),0.f);
          ry2[r]=fmaxf(y2+sig*(xbrd-xbp_),0.f);
          ry5[r]=fmaxf(y5+sig*(xbpu-xbru),0.f);
          ry6[r]=fmaxf(y6+sig*(xbpd-xbrd),0.f);
          if (last){
            if (lane == 0){
              st1(ws+O_XFIN+u, xp[r]);
              dap += Cost[u]*xp[r] + Crup[u]*xru[r] + Crdn[u]*xrd[r];
              out[u]=xp[r]; out[U+u]=xru[r]; out[2*U+u]=xrd[r];
            }
            if (lane < 16){
              out[3*U + u*16 + s] = xpu[r];
              out[3*U + U*S + u*16 + s] = xpd[r];
            }
          }
        } else {
          xp[r]=gp; xru[r]=gru; xrd[r]=grd; xpu[r]=gpu; xpd[r]=gpd;
          float d = gpu - gpd;
          if (lane == 0){ st1(ws+O_XBP+u, gp); e1p += gp; n2p += gp*gp+gru*gru+grd*grd; }
          if (lane < 16){ st1(ws+O_DIFF+u*16+s, d); a2p += d; n2p += gpu*gpu+gpd*gpd; }
        }
      }
    } else {
      const float4* ss4 = (const float4*)(lds + D_S78S);
#pragma unroll
      for (int r = 0; r < 3; ++r){
        int n = nbase + 176*r;
        if (n >= NN) break;
        const float* PT = ws + O_PTDFT + n*LN;  // read-only, L2-cached
        const float4* pt4 = (const float4*)PT;
        float g = dot4(pt4[lane], ss4[lane]) + dot4(pt4[lane+64], ss4[lane+64]);
        float pt = wred64(g);
        if (pd){
          float g1 = C_VIOL + pt + zsv, g2 = C_VIOL - pt - zsv;
          float xo = xsu[r]; xsu[r] = fmaxf(xo - tau*g1, 0.f); float xb1 = 2.f*xsu[r]-xo;
          xo = xsd[r];       xsd[r] = fmaxf(xo - tau*g2, 0.f); float xb2 = 2.f*xsd[r]-xo;
          if (lane == 0){
            st1(ws+O_SDIFF+n, xb1-xb2); susdp += xb1-xb2;
            if (last) dap += C_VIOL*(xsu[r] + xsd[r]);
          }
        } else {
          float gsu = pt + zsv;
          xsu[r] = gsu; xsd[r] = -gsu;
          if (lane == 0){ st1(ws+O_SDIFF+n, 2.f*gsu); susdp += 2.f*gsu; n2p += 2.f*gsu*gsu; }
        }
      }
    }
    float r1 = wred64(e1p);
    float r2 = wred64(susdp);
    float r3 = wred64(n2p + dap);
    if (lane == 0){
      atomicAdd(&lds[L_SACC+16], r1);
      atomicAdd(&lds[L_SACC+17], r2);
      atomicAdd(&lds[L_SACC+18], r3);
    }
    if (lane < 16) atomicAdd(&lds[L_SACC+s], a2p);
    __syncthreads();
    if (pd){
      if (tid < 10)
        st2(ws+O_PART+vbid*20+2*tid, make_float2(lds[L_SACC+2*tid], lds[L_SACC+2*tid+1]));
    } else {
      // device-scope atomics -> MALL (read back with agent loads only)
      if (tid < 16) atomicAdd(&ws[O_EQ2+(k+1)*16+tid], lds[L_SACC+tid]);
      else if (tid == 16) atomicAdd(&ws[O_EQ1+k+1], lds[L_SACC+16]);
      else if (tid == 17) atomicAdd(&ws[O_EQS+k+1], lds[L_SACC+17]);
      else if (tid == 18) atomicAdd(&ws[O_N2 +k+1], lds[L_SACC+18]);
    }
  };

  // ---- power iteration ----
  for (int kk = 0; kk <= N_POWER; ++kk){
    phaseY(false, kk); gbar();
    phaseX(false, kk, false); gbar();
  }

  // ---- step sizes ----
  {
    float Lop = sqrtf(sqrtf(ald(ws+O_N2+31)));
    tau = 0.9f/Lop; sig = 0.9f/Lop;
  }

  // ---- transition: zero register + exchange state ----
#pragma unroll
  for (int r=0;r<2;++r){ xp[r]=xru[r]=xrd[r]=xpu[r]=xpd[r]=0.f;
                         ry1[r]=ry2[r]=ry5[r]=ry6[r]=0.f;
                         ly3[r]=ly4[r]=ly7[r]=ly8[r]=0.f; }
#pragma unroll
  for (int r=0;r<3;++r){ xsu[r]=xsd[r]=0.f; }
  rz1 = rz2 = 0.f;
  for (int i = gtid; i < O_ZEND - O_MUT; i += NTH) ws[O_MUT+i] = 0.f;
  gbar();

  // ---- PDHG ----
  for (int it = 0; it < N_ITERS; ++it){
    phaseX(true, it, it == N_ITERS-1); gbar();
    if (it < N_ITERS-1){ phaseY(true, it); gbar(); }
  }

  // ---- epilogue: flows + DA cost ----
  for (int i = tid; i < 40; i += TPB){ ((float4*)(lds+L_XP))[i] = LDC4(O_XFIN+4*i); }
  __syncthreads();
#pragma unroll
  for (int j = 0; j < 2; ++j){
    const int l = 2*gw + j;
    const float* hg = ws + O_HG + l*U;
    float a = hg[lane]*lds[L_XP+lane] + hg[lane+64]*lds[L_XP+lane+64];
    if (lane < 32) a += hg[lane+128]*lds[L_XP+lane+128];
    float flow = wred64(a) + ws[O_CF+l];
    if (lane == 0){
      out[3*U + 2*U*S + l]      = Cap[l] - flow;
      out[3*U + 2*U*S + LN + l] = Cap[l] + flow;
    }
  }
  if (vbid == 0 && wv == 0){
    float da = (lane < WGN) ? ws[O_PART+lane*20+18] : 0.f;
    da = wred64(da);
    if (lane == 0) out[3*U + 2*U*S + 2*LN] = da;
  }
}

// ---------------- host entry ----------------
extern "C" void kernel_launch(void* const* d_in, const int* in_sizes, int n_in,
                              void* d_out, int out_size, void* d_ws, size_t ws_size,
                              hipStream_t stream){
  const float* w_scen = (const float*)d_in[0];
  const float* Pmax   = (const float*)d_in[1];
  const float* Cost   = (const float*)d_in[2];
  const float* Crup   = (const float*)d_in[3];
  const float* Crdn   = (const float*)d_in[4];
  const float* PTDF   = (const float*)d_in[5];
  const float* nG     = (const float*)d_in[6];
  const float* nW     = (const float*)d_in[7];
  const float* nL     = (const float*)d_in[8];
  const float* Pd     = (const float*)d_in[9];
  const float* w_exp  = (const float*)d_in[10];
  const float* Cap    = (const float*)d_in[11];
  float* ws  = (float*)d_ws;
  float* out = (float*)d_out;

  k_zero<<<dim3(64),  dim3(256), 0, stream>>>(ws);
  k_pdl <<<dim3(NN),  dim3(64),  0, stream>>>(nL, Pd, ws);
  k_hg  <<<dim3(LN),  dim3(U),   0, stream>>>(PTDF, nG, ws);
  k_hw  <<<dim3(LN),  dim3(W_),  0, stream>>>(PTDF, nW, ws);
  k_tp  <<<dim3(NN),  dim3(256), 0, stream>>>(PTDF, ws);
  k_misc<<<dim3(LN),  dim3(64),  0, stream>>>(PTDF, w_exp, w_scen, Cap, ws);
  k_scal<<<dim3(1),   dim3(256), 0, stream>>>(Pd, w_exp, w_scen, ws);
  k_solver<<<dim3(LAUNCH_WGN), dim3(TPB), 0, stream>>>(ws, Pmax, Cost, Crup, Crdn, PTDF, Cap, out);
}

// Round 7
// 4690.766 us; speedup vs baseline: 1.8513x; 1.4832x over previous
//
#include <hip/hip_runtime.h>
#include <math.h>

// ---------------- problem constants ----------------
constexpr int U  = 160;
constexpr int LN = 512;
constexpr int NN = 400;
constexpr int S  = 16;
constexpr int W_ = 64;
constexpr float C_VIOL = 2.0e4f;
constexpr int N_ITERS = 500;
constexpr int N_POWER = 30;

#define WGN 32
#define TPB 512
#define NTH (WGN*TPB)
#define LAUNCH_WGN 256   // elect 32 WGs on one XCD; others exit

constexpr int al4(int x){ return (x+3)&~3; }

// ---------------- ws layout (floats) ----------------
constexpr int O_HG    = 0;                 // Hg[LN][U]
constexpr int O_HGT   = O_HG   + LN*U;     // HgT[U][LN]
constexpr int O_PTDFT = O_HGT  + U*LN;     // PTDFT[NN][LN]
constexpr int O_HW    = O_PTDFT+ NN*LN;    // Hw[LN][W]
constexpr int O_PDL   = O_HW   + LN*W_;    // node_L@Pd [NN]
constexpr int O_CF    = al4(O_PDL + NN);   // const_flow [LN]
constexpr int O_B3    = O_CF   + LN;
constexpr int O_B4    = O_B3   + LN;
constexpr int O_BWS   = O_B4   + LN;       // b_ws[LN][S]
constexpr int O_BE1   = O_BWS  + LN*S;
constexpr int O_BE2   = al4(O_BE1 + 1);    // [S]
// mutable exchange (CU-scope plain access; L2-resident on elected XCD)
constexpr int O_MUT   = al4(O_BE2 + S);
constexpr int O_XBP   = O_MUT;             // [160] xb_p
constexpr int O_XFIN  = O_XBP  + 160;      // [160] final p
constexpr int O_DIFF  = O_XFIN + 160;      // [160][16]
constexpr int O_SDIFF = O_DIFF + 2560;     // [400]
constexpr int O_S78   = al4(O_SDIFF+400);  // [512][16]
constexpr int O_SW    = O_S78  + 8192;     // [512][2]: (w34, s78s)
constexpr int O_Z     = O_SW   + 1024;     // [20]: 0=z1 1=zs 2..17=z2
constexpr int O_PART  = O_Z    + 20;       // [32][20]
constexpr int O_ZEND  = O_PART + 640;
// device-atomic accumulators (MALL; agent-scope loads ONLY)
constexpr int O_N2    = O_ZEND;            // [32]
constexpr int O_EQ1   = O_N2   + 32;       // [32]
constexpr int O_EQ2   = O_EQ1  + 32;       // [32][16]
constexpr int O_EQS   = O_EQ2  + 512;      // [32]
constexpr int O_ARR   = O_EQS  + 32;       // [32*16] barrier flags (64B spaced)
constexpr int O_ELC   = O_ARR  + WGN*16;   // [8*16] per-XCD election counters
constexpr int O_ELT   = O_ELC  + 128;      // total election counter
constexpr int WSF     = O_ELT  + 16;

// ---------------- LDS layout (floats) ----------------
constexpr int L_SACC = 0;                  // [20]
constexpr int L_P    = al4(L_SACC + 20);   // [32][20] (WG0 stage of PART)
constexpr int L_HG   = al4(L_P + 640);     // [16][160] my 16 Hg line-rows
constexpr int L_HGT  = L_HG + 2560;        // [5][512]  my 5 HgT u-rows
constexpr int L_DYN  = al4(L_HGT + 2560);
// phase Y:
constexpr int L_XP = L_DYN;                // [160]
constexpr int L_SD = L_XP + 160;           // [400]
constexpr int L_DF = L_SD + 400;           // [160][17]
// phase X:
constexpr int D_S78T = L_DYN;              // [16][516]
constexpr int D_W34  = D_S78T + 16*516;    // [512]
constexpr int D_S78S = D_W34 + 512;        // [512]
constexpr int L_TOT  = D_S78S + 512;       // ~15060 floats ≈ 58.9 KB

// ---------------- device helpers ----------------
__device__ __forceinline__ float wred64(float v){
#pragma unroll
  for (int o = 32; o > 0; o >>= 1) v += __shfl_xor(v, o, 64);
  return v;
}
__device__ __forceinline__ float red16(float v){
  v += __shfl_xor(v, 1, 64); v += __shfl_xor(v, 2, 64);
  v += __shfl_xor(v, 4, 64); v += __shfl_xor(v, 8, 64);
  return v;
}
__device__ __forceinline__ float redchunk(float v){
  v += __shfl_xor(v, 16, 64); v += __shfl_xor(v, 32, 64);
  return v;
}
__device__ __forceinline__ float dot4(float4 a, float4 b){
  return a.x*b.x + a.y*b.y + a.z*b.z + a.w*b.w;
}
// agent-scope (MALL) load — for device-atomic-written accumulators only
__device__ __forceinline__ float ald(const float* p){
  return __hip_atomic_load(p, __ATOMIC_RELAXED, __HIP_MEMORY_SCOPE_AGENT);
}
// workgroup-scope atomic load: forces a vector (vL1) load at CU scope
__device__ __forceinline__ float wgld(const float* p){
  return __hip_atomic_load(p, __ATOMIC_RELAXED, __HIP_MEMORY_SCOPE_WORKGROUP);
}

// ---------------- setup kernels ----------------
__global__ void k_zero(float* ws){
  int gt = blockIdx.x*blockDim.x + threadIdx.x;
  int nt = gridDim.x*blockDim.x;
  for (int i = gt; i < WSF - O_MUT; i += nt){
    int a = O_MUT + i;
    float v = 0.f;
    if (a >= O_XBP && a < O_XBP + 160) v = 1.f;   // power v0: p = ones
    if (a == O_EQ1) v = (float)U;                 // eq1(ones) = sum p
    ws[a] = v;
  }
}

__global__ void k_pdl(const float* nL, const float* Pd, float* ws){
  int n = blockIdx.x; int lane = threadIdx.x;
  float p = 0.f;
  for (int m = lane; m < NN; m += 64) p += nL[n*NN+m]*Pd[m];
  p = wred64(p);
  if (lane == 0) ws[O_PDL+n] = p;
}

__global__ void k_hg(const float* PTDF, const float* nG, float* ws){
  int l = blockIdx.x, u = threadIdx.x;
  float acc = 0.f;
  for (int n = 0; n < NN; ++n) acc += PTDF[l*NN+n]*nG[n*U+u];
  ws[O_HG + l*U + u]  = acc;
  ws[O_HGT + u*LN + l] = acc;
}

__global__ void k_hw(const float* PTDF, const float* nW, float* ws){
  int l = blockIdx.x, w = threadIdx.x;
  float acc = 0.f;
  for (int n = 0; n < NN; ++n) acc += PTDF[l*NN+n]*nW[n*W_+w];
  ws[O_HW + l*W_ + w] = acc;
}

__global__ void k_tp(const float* PTDF, float* ws){
  int n = blockIdx.x;
  for (int l = threadIdx.x; l < LN; l += blockDim.x)
    ws[O_PTDFT + n*LN + l] = PTDF[l*NN + n];
}

__global__ void k_misc(const float* PTDF, const float* w_exp, const float* w_scen,
                       const float* Cap, float* ws){
  int l = blockIdx.x; int lane = threadIdx.x;
  float part = ws[O_HW + l*W_ + lane]*w_exp[lane];
  for (int n = lane; n < NN; n += 64) part -= PTDF[l*NN+n]*ws[O_PDL+n];
  float cfv = wred64(part);
  if (lane == 0){
    ws[O_CF+l] = cfv;
    ws[O_B3+l] = Cap[l] - cfv;
    ws[O_B4+l] = Cap[l] + cfv;
  }
  int s = lane & 15, ch = lane >> 4;
  float bp = 0.f;
  for (int w = ch*16; w < ch*16+16; ++w) bp += ws[O_HW + l*W_ + w]*w_scen[s*W_+w];
  bp = redchunk(bp);
  if (lane < 16) ws[O_BWS + l*S + s] = bp;
}

__global__ void k_scal(const float* Pd, const float* w_exp, const float* w_scen, float* ws){
  __shared__ float sr[256];
  int tid = threadIdx.x;
  float p = 0.f;
  for (int i = tid; i < NN; i += 256) p += Pd[i];
  for (int i = tid; i < W_; i += 256) p -= w_exp[i];
  sr[tid] = p; __syncthreads();
  for (int o = 128; o > 0; o >>= 1){ if (tid < o) sr[tid] += sr[tid+o]; __syncthreads(); }
  if (tid == 0) ws[O_BE1] = sr[0];
  if (tid < S){
    float a = 0.f;
    for (int w = 0; w < W_; ++w) a += w_scen[tid*W_+w];
    ws[O_BE2+tid] = -a;
  }
}

// ---------------- persistent solver ----------------
extern "C" __global__ void __launch_bounds__(TPB)
k_solver(float* __restrict__ ws, const float* __restrict__ Pmax,
         const float* __restrict__ Cost, const float* __restrict__ Crup,
         const float* __restrict__ Crdn, const float* __restrict__ PTDF,
         const float* __restrict__ Cap, float* __restrict__ out)
{
  const int tid  = threadIdx.x;
  const int lane = tid & 63;
  const int wv   = tid >> 6;
  const int s = lane & 15, ch = lane >> 4;
  unsigned nbar = 0;
  __shared__ __align__(16) float lds[L_TOT];
  __shared__ int s_vb;

  // ---- election: pick 32 WGs on the most-populated XCD ----
  if (tid == 0){
    int xcc;
    asm volatile("s_getreg_b32 %0, hwreg(HW_REG_XCC_ID)" : "=s"(xcc));
    xcc &= 7;
    int* elc = (int*)(ws + O_ELC);
    int* elt = (int*)(ws + O_ELT);
    int rank = __hip_atomic_fetch_add(&elc[xcc*16], 1, __ATOMIC_RELAXED,
                                      __HIP_MEMORY_SCOPE_AGENT);
    __threadfence();
    __hip_atomic_fetch_add(elt, 1, __ATOMIC_RELEASE, __HIP_MEMORY_SCOPE_AGENT);
    while (__hip_atomic_load(elt, __ATOMIC_ACQUIRE, __HIP_MEMORY_SCOPE_AGENT)
           < LAUNCH_WGN)
      __builtin_amdgcn_s_sleep(2);
    __threadfence();
    int best = 0, bc = -1;
    for (int x = 0; x < 8; ++x){
      int c = __hip_atomic_load(&elc[x*16], __ATOMIC_RELAXED,
                                __HIP_MEMORY_SCOPE_AGENT);
      if (c > bc){ bc = c; best = x; }
    }
    s_vb = (xcc == best && rank < WGN) ? rank : -1;
  }
  __syncthreads();
  const int vbid = s_vb;
  if (vbid < 0) return;

  const int gtid = vbid*TPB + tid;

  // plain CU-scope accessors (L2-resident exchange)
  auto LDC4 = [&](int e)->float4{ return *(const float4*)(ws + e); };
  auto st1  = [&](float* p, float v){ *p = v; };
  auto st2  = [&](float* p, float2 v){ *(float2*)p = v; };

  // work roles: every WG identical mix
  const bool isU = (wv < 5);
  const int  u   = vbid*5 + wv;          // valid if isU (0..159)
  const int  nw  = vbid*3 + (wv-5);      // n-wave index 0..95 if wv>=5
  const int  NR  = (!isU && nw < 16) ? 5 : 4;   // n = nw + 96r

  // ---- persistent LDS: my 16 Hg line-rows + my 5 HgT u-rows ----
  for (int i = tid; i < 2560; i += TPB) lds[L_HG + i]  = ws[O_HG  + vbid*2560 + i];
  for (int i = tid; i < 2560; i += TPB) lds[L_HGT + i] = ws[O_HGT + vbid*2560 + i];
  __syncthreads();

  // persistent register state
  float xp=1.f,xru=1.f,xrd=1.f,xpu=1.f,xpd=1.f;   // u-wave primal (power v0=1)
  float ry1=0.f,ry2=0.f,ry5=0.f,ry6=0.f;          // u-wave duals
  float xsu[5],xsd[5];                            // n-wave primal
  float ly3[2],ly4[2],ly7[2],ly8[2];              // line duals (2 lines/wave)
  float rz1=0.f, rz2=0.f;
  float tau=0.f, sig=0.f;
#pragma unroll
  for (int r=0;r<5;++r){ xsu[r]=xsd[r]=1.f; }
#pragma unroll
  for (int j=0;j<2;++j){ ly3[j]=ly4[j]=ly7[j]=ly8[j]=0.f; }

  // ---- L2-resident grid barrier: plain flags + vL1 invalidate in poll ----
  unsigned* arr = (unsigned*)(ws + O_ARR);
  auto gbar = [&](){
    ++nbar;
    asm volatile("s_waitcnt vmcnt(0)" ::: "memory");
    __syncthreads();
    if (tid < WGN){
      if (tid == vbid) *(volatile unsigned*)(arr + vbid*16) = nbar;
      volatile unsigned* f = (volatile unsigned*)(arr + tid*16);
      while (true){
        asm volatile("buffer_inv" ::: "memory");
        asm volatile("s_waitcnt vmcnt(0)" ::: "memory");
        if (*f >= nbar) break;
      }
    }
    __syncthreads();
  };

  // ---- phase Y: per-line A-apply (power) / dual update (pdhg) ----
  auto phaseY = [&](bool pd, int k){
    float scl = 1.f;
    if (!pd && k > 0) scl = 1.f/sqrtf(ald(ws+O_N2+k));
    for (int i = tid; i < 40; i += TPB){ ((float4*)(lds+L_XP))[i] = LDC4(O_XBP+4*i); }
    for (int i = tid; i < 100; i += TPB){ ((float4*)(lds+L_SD))[i] = LDC4(O_SDIFF+4*i); }
    for (int i = tid; i < 640; i += TPB){
      float4 v = LDC4(O_DIFF+4*i);
      int e = 4*i, uu = e >> 4, s0 = e & 15;
      float* d = lds + L_DF + uu*17 + s0;
      d[0]=v.x; d[1]=v.y; d[2]=v.z; d[3]=v.w;
    }
    if (pd && vbid == 0){
      for (int i = tid; i < 160; i += TPB){ ((float4*)(lds+L_P))[i] = LDC4(O_PART+4*i); }
    }
    __syncthreads();

    if (pd && vbid == 0 && wv == 7){
      float acc = 0.f;
      if (lane < 18){
        for (int i = 0; i < WGN; ++i) acc += lds[L_P + i*20 + lane];
      }
      float susd = __shfl(acc, 17, 64);
      float ae1  = __shfl(acc, 16, 64);
      if (lane < 16){
        rz2 += sig*((acc + susd) - ws[O_BE2+lane]);
        st1(ws+O_Z+2+lane, rz2);
      }
      float zst = red16((lane < 16) ? rz2 : 0.f);
      if (lane == 0) st1(ws+O_Z+1, zst);
      if (lane == 16){ rz1 += sig*(ae1 - ws[O_BE1]); st1(ws+O_Z+0, rz1); }
    }

#pragma unroll
    for (int j = 0; j < 2; ++j){
      const int l = vbid*16 + wv*2 + j;
      const float* hgl = lds + L_HG + (wv*2+j)*160;   // LDS-resident Hg row
      float a = hgl[lane]*lds[L_XP+lane] + hgl[lane+64]*lds[L_XP+lane+64];
      if (lane < 32) a += hgl[lane+128]*lds[L_XP+lane+128];
      float fp = wred64(a);
      const float4* pr  = (const float4*)(PTDF + l*NN);
      const float4* sd4 = (const float4*)(lds + L_SD);
      float b = dot4(pr[lane], sd4[lane]);
      if (lane < 36) b += dot4(pr[lane+64], sd4[lane+64]);
      float pn = wred64(b);
      const float* hgc = hgl + ch*40;
      const float* dfc = lds + L_DF + (ch*40)*17 + s;
      float sc = 0.f;
#pragma unroll 8
      for (int i = 0; i < 40; ++i) sc += hgc[i]*dfc[i*17];
      sc = redchunk(sc);
      float scen = sc + fp + pn;
      float b3l = ws[O_B3+l], b4l = ws[O_B4+l];
      float sv;
      if (pd){
        float bw = ws[O_BWS + l*16 + s];
        ly7[j] = fmaxf(ly7[j] + sig*( scen - (b3l - bw)), 0.f);
        ly8[j] = fmaxf(ly8[j] + sig*(-scen - (b4l + bw)), 0.f);
        sv = ly7[j] - ly8[j];
        ly3[j] = fmaxf(ly3[j] + sig*( fp - b3l), 0.f);
        ly4[j] = fmaxf(ly4[j] + sig*(-fp - b4l), 0.f);
      } else {
        sv = 2.f*scen*scl;
        ly3[j] = fp*scl; ly4[j] = -fp*scl;
      }
      if (lane < 16) st1(ws+O_S78 + l*16 + s, sv);
      float ssum = red16(sv);
      if (lane == 0) st2(ws+O_SW + 2*l, make_float2(ly3[j]-ly4[j]+ssum, ssum));
    }
  };

  // ---- phase X: AT-apply + primal update ----
  auto phaseX = [&](bool pd, int k, bool last){
    if (tid < 20) lds[L_SACC+tid] = 0.f;
    // stage S78 (transposed) + W34 + S78S — every WG
    for (int i = tid; i < 2048; i += TPB){
      float4 v = LDC4(O_S78+4*i);
      int e = 4*i, ll = e >> 4, s0 = e & 15;
      lds[D_S78T + (s0  )*516 + ll] = v.x;
      lds[D_S78T + (s0+1)*516 + ll] = v.y;
      lds[D_S78T + (s0+2)*516 + ll] = v.z;
      lds[D_S78T + (s0+3)*516 + ll] = v.w;
    }
    for (int i = tid; i < 256; i += TPB){
      float4 v = LDC4(O_SW+4*i);
      lds[D_W34+2*i]  = v.x; lds[D_W34+2*i+1]  = v.z;
      lds[D_S78S+2*i] = v.y; lds[D_S78S+2*i+1] = v.w;
    }
    float scl = 1.f, z1v, z2v, zsv;
    if (pd){
      z1v = wgld(ws+O_Z+0); z2v = ws[O_Z+2+s]; zsv = wgld(ws+O_Z+1);
    } else {
      if (k > 0) scl = 1.f/sqrtf(ald(ws+O_N2+k));
      z1v = ald(ws+O_EQ1+k)*scl;
      z2v = (ald(ws+O_EQ2+k*16+s) + ald(ws+O_EQS+k))*scl;
      zsv = red16(z2v);
    }
    __syncthreads();

    float n2p=0.f, e1p=0.f, a2p=0.f, susdp=0.f, dap=0.f;
    if (isU){
      float y1,y2,y5,y6;
      if (pd){ y1=ry1; y2=ry2; y5=ry5; y6=ry6; }
      else {
        y1=(xp+xru)*scl; y2=(xrd-xp)*scl;
        y5=(xpu-xru)*scl; y6=(xpd-xrd)*scl;
      }
      const float* HT = lds + L_HGT + wv*512;        // LDS-resident HgT row
      const float4* ht4 = (const float4*)HT;
      const float4* w4  = (const float4*)(lds + D_W34);
      float g = dot4(ht4[lane], w4[lane]) + dot4(ht4[lane+64], w4[lane+64]);
      float gdot = wred64(g);
      const float4* sc4f = (const float4*)(lds + D_S78T + s*516);
      float h = 0.f;
#pragma unroll 8
      for (int k2 = 0; k2 < 32; ++k2) h += dot4(ht4[4*k2+ch], sc4f[4*k2+ch]);
      h = redchunk(h);
      float t5 = red16(y5), t6 = red16(y6);
      float gpu = y5 + h + z2v;
      float gpd = y6 - h - z2v;
      float gp  = y1 - y2 + gdot + z1v;
      float gru = y1 - t5;
      float grd = y2 - t6;
      if (pd){
        float xo;
        xo=xp;  xp =fmaxf(xo-tau*(Cost[u]+gp ),0.f); float xbp_=2.f*xp -xo;
        xo=xru; xru=fmaxf(xo-tau*(Crup[u]+gru),0.f); float xbru=2.f*xru-xo;
        xo=xrd; xrd=fmaxf(xo-tau*(Crdn[u]+grd),0.f); float xbrd=2.f*xrd-xo;
        xo=xpu; xpu=fmaxf(xo-tau*gpu,0.f);           float xbpu=2.f*xpu-xo;
        xo=xpd; xpd=fmaxf(xo-tau*gpd,0.f);           float xbpd=2.f*xpd-xo;
        float d = xbpu - xbpd;
        if (lane == 0){ st1(ws+O_XBP+u, xbp_); e1p += xbp_; }
        if (lane < 16){ st1(ws+O_DIFF+u*16+s, d); a2p += d; }
        ry1=fmaxf(y1+sig*(xbp_+xbru-Pmax[u]),0.f);
        ry2=fmaxf(y2+sig*(xbrd-xbp_),0.f);
        ry5=fmaxf(y5+sig*(xbpu-xbru),0.f);
        ry6=fmaxf(y6+sig*(xbpd-xbrd),0.f);
        if (last){
          if (lane == 0){
            st1(ws+O_XFIN+u, xp);
            dap += Cost[u]*xp + Crup[u]*xru + Crdn[u]*xrd;
            out[u]=xp; out[U+u]=xru; out[2*U+u]=xrd;
          }
          if (lane < 16){
            out[3*U + u*16 + s] = xpu;
            out[3*U + U*S + u*16 + s] = xpd;
          }
        }
      } else {
        xp=gp; xru=gru; xrd=grd; xpu=gpu; xpd=gpd;
        float d = gpu - gpd;
        if (lane == 0){ st1(ws+O_XBP+u, gp); e1p += gp; n2p += gp*gp+gru*gru+grd*grd; }
        if (lane < 16){ st1(ws+O_DIFF+u*16+s, d); a2p += d; n2p += gpu*gpu+gpd*gpd; }
      }
    } else {
      const float4* ss4 = (const float4*)(lds + D_S78S);
#pragma unroll
      for (int r = 0; r < 5; ++r){
        if (r >= NR) break;
        int n = nw + 96*r;
        const float* PT = ws + O_PTDFT + n*LN;       // global, L2 (pipelined)
        const float4* pt4 = (const float4*)PT;
        float g = dot4(pt4[lane], ss4[lane]) + dot4(pt4[lane+64], ss4[lane+64]);
        float pt = wred64(g);
        if (pd){
          float g1 = C_VIOL + pt + zsv, g2 = C_VIOL - pt - zsv;
          float xo = xsu[r]; xsu[r] = fmaxf(xo - tau*g1, 0.f); float xb1 = 2.f*xsu[r]-xo;
          xo = xsd[r];       xsd[r] = fmaxf(xo - tau*g2, 0.f); float xb2 = 2.f*xsd[r]-xo;
          if (lane == 0){
            st1(ws+O_SDIFF+n, xb1-xb2); susdp += xb1-xb2;
            if (last) dap += C_VIOL*(xsu[r] + xsd[r]);
          }
        } else {
          float gsu = pt + zsv;
          xsu[r] = gsu; xsd[r] = -gsu;
          if (lane == 0){ st1(ws+O_SDIFF+n, 2.f*gsu); susdp += 2.f*gsu; n2p += 2.f*gsu*gsu; }
        }
      }
    }
    float r1 = wred64(e1p);
    float r2 = wred64(susdp);
    float r3 = wred64(n2p + dap);
    if (lane == 0){
      atomicAdd(&lds[L_SACC+16], r1);
      atomicAdd(&lds[L_SACC+17], r2);
      atomicAdd(&lds[L_SACC+18], r3);
    }
    if (lane < 16) atomicAdd(&lds[L_SACC+s], a2p);
    __syncthreads();
    if (pd){
      if (tid < 10)
        st2(ws+O_PART+vbid*20+2*tid, make_float2(lds[L_SACC+2*tid], lds[L_SACC+2*tid+1]));
    } else {
      if (tid < 16) atomicAdd(&ws[O_EQ2+(k+1)*16+tid], lds[L_SACC+tid]);
      else if (tid == 16) atomicAdd(&ws[O_EQ1+k+1], lds[L_SACC+16]);
      else if (tid == 17) atomicAdd(&ws[O_EQS+k+1], lds[L_SACC+17]);
      else if (tid == 18) atomicAdd(&ws[O_N2 +k+1], lds[L_SACC+18]);
    }
  };

  // ---- power iteration ----
  for (int kk = 0; kk <= N_POWER; ++kk){
    phaseY(false, kk); gbar();
    phaseX(false, kk, false); gbar();
  }

  // ---- step sizes ----
  {
    float Lop = sqrtf(sqrtf(ald(ws+O_N2+31)));
    tau = 0.9f/Lop; sig = 0.9f/Lop;
  }

  // ---- transition: zero register + exchange state ----
  xp=xru=xrd=xpu=xpd=0.f; ry1=ry2=ry5=ry6=0.f; rz1=rz2=0.f;
#pragma unroll
  for (int r=0;r<5;++r){ xsu[r]=xsd[r]=0.f; }
#pragma unroll
  for (int j=0;j<2;++j){ ly3[j]=ly4[j]=ly7[j]=ly8[j]=0.f; }
  for (int i = gtid; i < O_ZEND - O_MUT; i += NTH) ws[O_MUT+i] = 0.f;
  gbar();

  // ---- PDHG ----
  for (int it = 0; it < N_ITERS; ++it){
    phaseX(true, it, it == N_ITERS-1); gbar();
    if (it < N_ITERS-1){ phaseY(true, it); gbar(); }
  }

  // ---- epilogue: flows + DA cost ----
  for (int i = tid; i < 40; i += TPB){ ((float4*)(lds+L_XP))[i] = LDC4(O_XFIN+4*i); }
  __syncthreads();
#pragma unroll
  for (int j = 0; j < 2; ++j){
    const int l = vbid*16 + wv*2 + j;
    const float* hgl = lds + L_HG + (wv*2+j)*160;
    float a = hgl[lane]*lds[L_XP+lane] + hgl[lane+64]*lds[L_XP+lane+64];
    if (lane < 32) a += hgl[lane+128]*lds[L_XP+lane+128];
    float flow = wred64(a) + ws[O_CF+l];
    if (lane == 0){
      out[3*U + 2*U*S + l]      = Cap[l] - flow;
      out[3*U + 2*U*S + LN + l] = Cap[l] + flow;
    }
  }
  if (vbid == 0 && wv == 0){
    float da = (lane < WGN) ? ws[O_PART+lane*20+18] : 0.f;
    da = wred64(da);
    if (lane == 0) out[3*U + 2*U*S + 2*LN] = da;
  }
}

// ---------------- host entry ----------------
extern "C" void kernel_launch(void* const* d_in, const int* in_sizes, int n_in,
                              void* d_out, int out_size, void* d_ws, size_t ws_size,
                              hipStream_t stream){
  const float* w_scen = (const float*)d_in[0];
  const float* Pmax   = (const float*)d_in[1];
  const float* Cost   = (const float*)d_in[2];
  const float* Crup   = (const float*)d_in[3];
  const float* Crdn   = (const float*)d_in[4];
  const float* PTDF   = (const float*)d_in[5];
  const float* nG     = (const float*)d_in[6];
  const float* nW     = (const float*)d_in[7];
  const float* nL     = (const float*)d_in[8];
  const float* Pd     = (const float*)d_in[9];
  const float* w_exp  = (const float*)d_in[10];
  const float* Cap    = (const float*)d_in[11];
  float* ws  = (float*)d_ws;
  float* out = (float*)d_out;

  k_zero<<<dim3(64),  dim3(256), 0, stream>>>(ws);
  k_pdl <<<dim3(NN),  dim3(64),  0, stream>>>(nL, Pd, ws);
  k_hg  <<<dim3(LN),  dim3(U),   0, stream>>>(PTDF, nG, ws);
  k_hw  <<<dim3(LN),  dim3(W_),  0, stream>>>(PTDF, nW, ws);
  k_tp  <<<dim3(NN),  dim3(256), 0, stream>>>(PTDF, ws);
  k_misc<<<dim3(LN),  dim3(64),  0, stream>>>(PTDF, w_exp, w_scen, Cap, ws);
  k_scal<<<dim3(1),   dim3(256), 0, stream>>>(Pd, w_exp, w_scen, ws);
  k_solver<<<dim3(LAUNCH_WGN), dim3(TPB), 0, stream>>>(ws, Pmax, Cost, Crup, Crdn, PTDF, Cap, out);
}